// Round 8
// baseline (155.209 us; speedup 1.0000x reference)
//
#include <hip/hip_runtime.h>
#include <math.h>

#define C_C   0.01f
#define SQC   0.1f          // sqrt(c)
#define EPSF  1e-15f
#define TCLIP (1.0f - 1e-6f)

typedef short short8 __attribute__((ext_vector_type(8)));
typedef float f32x4  __attribute__((ext_vector_type(4)));

__device__ __forceinline__ float wred(float v) {
#pragma unroll
    for (int off = 32; off > 0; off >>= 1) v += __shfl_xor(v, off, 64);
    return v;
}

__device__ __forceinline__ float dot4(const float4& a, const float4& b) {
    return a.x * b.x + a.y * b.y + a.z * b.z + a.w * b.w;
}

// fp32 -> bf16 round-nearest-even, raw bits
__device__ __forceinline__ unsigned int f2bf(float f) {
    unsigned int u = __float_as_uint(f);
    u += 0x7fffu + ((u >> 16) & 1u);
    return u >> 16;
}
__device__ __forceinline__ unsigned int pk2(float a, float b) {
    return f2bf(a) | (f2bf(b) << 16);
}

// ---------------------------------------------------------------------------
// Kernel 1: build 128 queries; emit bf16 rows + fp32 q2 + subject bias.
// One wave per query.
// ---------------------------------------------------------------------------
__global__ __launch_bounds__(64)
void build_queries(const float* __restrict__ ent,
                   const float* __restrict__ rrot,
                   const float* __restrict__ rtrans,
                   const float* __restrict__ ebias,
                   const int* __restrict__ trip,
                   unsigned short* __restrict__ qb,  // [B][512] bf16 bits
                   float* __restrict__ q2buf,        // [B]
                   float* __restrict__ sbbuf)        // [B]
{
    const int b    = blockIdx.x;
    const int lane = threadIdx.x;
    const int t0   = trip[b * 3 + 0];
    const int r    = trip[b * 3 + 1];

    const float* srow = ent + (size_t)t0 * 512;
    float4 s0 = *(const float4*)(srow + 4 * lane);
    float4 s1 = *(const float4*)(srow + 256 + 4 * lane);

    // log_map_zero
    float ss = dot4(s0, s0) + dot4(s1, s1);
    ss = wred(ss);
    float yn  = fmaxf(sqrtf(ss), EPSF);
    float arg = fminf(SQC * yn, TCLIP);
    float fl  = atanhf(arg) / (SQC * yn);

    // givens rotation on s_tan = fl * s
    const float* arow = rrot + (size_t)r * 256;
    float2 a01 = *(const float2*)(arow + 2 * lane);
    float2 a23 = *(const float2*)(arow + 128 + 2 * lane);
    float c0, n0, c1, n1, c2, n2, c3, n3;
    sincosf(a01.x, &n0, &c0);
    sincosf(a01.y, &n1, &c1);
    sincosf(a23.x, &n2, &c2);
    sincosf(a23.y, &n3, &c3);

    float t0x = s0.x * fl, t0y = s0.y * fl, t0z = s0.z * fl, t0w = s0.w * fl;
    float t1x = s1.x * fl, t1y = s1.y * fl, t1z = s1.z * fl, t1w = s1.w * fl;

    float4 r0, r1;
    r0.x = c0 * t0x - n0 * t0y;  r0.y = n0 * t0x + c0 * t0y;
    r0.z = c1 * t0z - n1 * t0w;  r0.w = n1 * t0z + c1 * t0w;
    r1.x = c2 * t1x - n2 * t1y;  r1.y = n2 * t1x + c2 * t1y;
    r1.z = c3 * t1z - n3 * t1w;  r1.w = n3 * t1z + c3 * t1w;

    // exp_map_zero(rot)
    float vv = dot4(r0, r0) + dot4(r1, r1);
    vv = wred(vv);
    float vn = fmaxf(sqrtf(vv), EPSF);
    float fx = tanhf(SQC * vn) / (SQC * vn);

    // exp_map_zero(rel_trans)
    const float* trow = rtrans + (size_t)r * 512;
    float4 u0 = *(const float4*)(trow + 4 * lane);
    float4 u1 = *(const float4*)(trow + 256 + 4 * lane);
    float tt = dot4(u0, u0) + dot4(u1, u1);
    float rt = dot4(r0, u0) + dot4(r1, u1);
    tt = wred(tt);
    rt = wred(rt);
    float tn = fmaxf(sqrtf(tt), EPSF);
    float fy = tanhf(SQC * tn) / (SQC * tn);

    // mobius_add(x = fx*rot, y = fy*trans)
    float x2 = fx * fx * vv;
    float y2 = fy * fy * tt;
    float xy = fx * fy * rt;
    float ca  = 1.0f + 2.0f * C_C * xy + C_C * y2;
    float cb  = 1.0f - C_C * x2;
    float den = fmaxf(1.0f + 2.0f * C_C * xy + C_C * C_C * x2 * y2, EPSF);
    float inv = 1.0f / den;

    float4 q0, q1;
    q0.x = (ca * fx * r0.x + cb * fy * u0.x) * inv;
    q0.y = (ca * fx * r0.y + cb * fy * u0.y) * inv;
    q0.z = (ca * fx * r0.z + cb * fy * u0.z) * inv;
    q0.w = (ca * fx * r0.w + cb * fy * u0.w) * inv;
    q1.x = (ca * fx * r1.x + cb * fy * u1.x) * inv;
    q1.y = (ca * fx * r1.y + cb * fy * u1.y) * inv;
    q1.z = (ca * fx * r1.z + cb * fy * u1.z) * inv;
    q1.w = (ca * fx * r1.w + cb * fy * u1.w) * inv;

    float qq = dot4(q0, q0) + dot4(q1, q1);
    qq = wred(qq);

    unsigned short* qrow = qb + (size_t)b * 512;
    uint2 h0, h1;
    h0.x = pk2(q0.x, q0.y);  h0.y = pk2(q0.z, q0.w);
    h1.x = pk2(q1.x, q1.y);  h1.y = pk2(q1.z, q1.w);
    *(uint2*)(qrow + 4 * lane)       = h0;
    *(uint2*)(qrow + 256 + 4 * lane) = h1;
    if (lane == 0) {
        q2buf[b] = qq;
        sbbuf[b] = ebias[t0];
    }
}

// ---------------------------------------------------------------------------
// Kernel 2: bf16-MFMA scoring, pipelined.
// Block = 128 q x 128 e, 4 waves (2x2), wave tile 64x64, BK=64 (8 K-slabs).
// Double-buffered LDS (2 x (16KB Q + 16KB E)) + register prefetch:
//   per iter: issue global loads(t+1) -> MFMA on LDS[cur] -> convert+write
//   LDS[cur^1] -> ONE barrier. HBM latency hides under MFMA.
// 16B LDS slots XOR-swizzled by (row&7)<<4 (conflict-free b128 r/w).
// e2 accumulated in fp32 during conversion; shfl-pair reduce at end.
// Grid = 320 blocks, 2 blocks/CU (64KB LDS) -> all co-resident, no tail.
// ---------------------------------------------------------------------------
__global__ __launch_bounds__(256)
void score_mfma(const float* __restrict__ ent,
                const float* __restrict__ ebias,
                const unsigned short* __restrict__ qb,
                const float* __restrict__ q2buf,
                const float* __restrict__ sbbuf,
                float* __restrict__ out, int E)
{
    __shared__ unsigned short qs[2][128 * 64];  // 2 x 16 KB
    __shared__ unsigned short es[2][128 * 64];  // 2 x 16 KB
    __shared__ float e2s[128];

    const int tid  = threadIdx.x;
    const int lane = tid & 63;
    const int wid  = tid >> 6;   // 0..3
    const int wr   = wid >> 1;   // q half (64 rows)
    const int wc   = wid & 1;    // e half (64 cols)
    const int e0   = blockIdx.x * 128;

    const int row  = tid >> 1;   // staging row 0..127 (both tiles)
    const int half = tid & 1;    // staging col half (32 elems)

    f32x4 acc[4][4];
#pragma unroll
    for (int mi = 0; mi < 4; ++mi)
#pragma unroll
        for (int nj = 0; nj < 4; ++nj) acc[mi][nj] = (f32x4)0.0f;

    uint4  qreg[4];
    float4 ereg[8];
    float  e2p = 0.0f;

    const unsigned short* qsrc0 = qb + (size_t)row * 512 + half * 32;
    const float*          esrc0 = ent + (size_t)(e0 + row) * 512 + half * 32;

#define LOAD_TILES(K0)                                                    \
    {                                                                     \
        const unsigned short* qsrc = qsrc0 + (K0);                        \
        _Pragma("unroll")                                                 \
        for (int c = 0; c < 4; ++c) qreg[c] = *(const uint4*)(qsrc + c * 8); \
        const float* esrc = esrc0 + (K0);                                 \
        _Pragma("unroll")                                                 \
        for (int c = 0; c < 8; ++c) ereg[c] = *(const float4*)(esrc + c * 4); \
    }

#define STORE_TILES(BUF)                                                  \
    {                                                                     \
        _Pragma("unroll")                                                 \
        for (int c = 0; c < 4; ++c) {                                     \
            int off = row * 128 + ((((half * 4 + c) * 16)) ^ ((row & 7) << 4)); \
            *(uint4*)((char*)qs[BUF] + off) = qreg[c];                    \
        }                                                                 \
        _Pragma("unroll")                                                 \
        for (int p = 0; p < 4; ++p) {                                     \
            float4 f0 = ereg[2 * p], f1 = ereg[2 * p + 1];                \
            e2p += dot4(f0, f0) + dot4(f1, f1);                           \
            uint4 pkd = { pk2(f0.x, f0.y), pk2(f0.z, f0.w),               \
                          pk2(f1.x, f1.y), pk2(f1.z, f1.w) };             \
            int off = row * 128 + ((((half * 4 + p) * 16)) ^ ((row & 7) << 4)); \
            *(uint4*)((char*)es[BUF] + off) = pkd;                        \
        }                                                                 \
    }

    // prologue: slab 0
    LOAD_TILES(0);
    STORE_TILES(0);
    __syncthreads();

    int cur = 0;
#pragma unroll
    for (int t = 0; t < 8; ++t) {
        if (t < 7) LOAD_TILES((t + 1) * 64);

        // compute on LDS[cur]
#pragma unroll
        for (int ks = 0; ks < 2; ++ks) {
            const int kb = (ks * 4 + (lane >> 4)) * 16;  // 16B slot byte off
            short8 a[4], b[4];
#pragma unroll
            for (int mi = 0; mi < 4; ++mi) {
                int r = wr * 64 + mi * 16 + (lane & 15);
                a[mi] = *(const short8*)((const char*)qs[cur] +
                         r * 128 + (kb ^ ((r & 7) << 4)));
            }
#pragma unroll
            for (int nj = 0; nj < 4; ++nj) {
                int r = wc * 64 + nj * 16 + (lane & 15);
                b[nj] = *(const short8*)((const char*)es[cur] +
                         r * 128 + (kb ^ ((r & 7) << 4)));
            }
#pragma unroll
            for (int mi = 0; mi < 4; ++mi)
#pragma unroll
                for (int nj = 0; nj < 4; ++nj)
                    acc[mi][nj] = __builtin_amdgcn_mfma_f32_16x16x32_bf16(
                        a[mi], b[nj], acc[mi][nj], 0, 0, 0);
        }

        if (t < 7) STORE_TILES(cur ^ 1);
        __syncthreads();
        cur ^= 1;
    }

    // e2: lanes 2t/2t+1 hold halves of row t's squared norm
    e2p += __shfl_xor(e2p, 1, 64);
    if (half == 0) e2s[row] = e2p;
    __syncthreads();

    // epilogue: closed-form mobius distance
    float e2v[4], bev[4];
#pragma unroll
    for (int nj = 0; nj < 4; ++nj) {
        int ecol = wc * 64 + nj * 16 + (lane & 15);
        e2v[nj] = e2s[ecol];
        bev[nj] = ebias[e0 + ecol];
    }
#pragma unroll
    for (int mi = 0; mi < 4; ++mi) {
        const int qbase = wr * 64 + mi * 16 + (lane >> 4) * 4;
        float q2a[4], sba[4];
#pragma unroll
        for (int r = 0; r < 4; ++r) {
            q2a[r] = q2buf[qbase + r];
            sba[r] = sbbuf[qbase + r];
        }
#pragma unroll
        for (int nj = 0; nj < 4; ++nj) {
            const int ecol = e0 + wc * 64 + nj * 16 + (lane & 15);
            const float e2 = e2v[nj];
            const float be = bev[nj];
#pragma unroll
            for (int r = 0; r < 4; ++r) {
                float q2  = q2a[r];
                float xy  = -acc[mi][nj][r];
                float ca  = 1.0f + 2.0f * C_C * xy + C_C * e2;
                float cb  = 1.0f - C_C * q2;
                float den = fmaxf(1.0f + 2.0f * C_C * xy + C_C * C_C * q2 * e2, EPSF);
                float id2 = 1.0f / (den * den);
                float dist = (ca * ca * q2 + 2.0f * ca * cb * xy + cb * cb * e2) * id2;
                out[(size_t)(qbase + r) * E + ecol] = sba[r] + be - dist;
            }
        }
    }
#undef LOAD_TILES
#undef STORE_TILES
}

extern "C" void kernel_launch(void* const* d_in, const int* in_sizes, int n_in,
                              void* d_out, int out_size, void* d_ws, size_t ws_size,
                              hipStream_t stream) {
    const float* ent    = (const float*)d_in[0];
    // d_in[1] = rel_embedding: unused by the reference
    const float* rrot   = (const float*)d_in[2];
    const float* rtrans = (const float*)d_in[3];
    const float* ebias  = (const float*)d_in[4];
    const int*   trip   = (const int*)d_in[5];
    float* out = (float*)d_out;

    const int B = in_sizes[5] / 3;    // 128
    const int E = in_sizes[0] / 512;  // 40960

    unsigned short* qb = (unsigned short*)d_ws;          // B*512 bf16
    float* q2buf = (float*)(qb + (size_t)B * 512);       // B floats
    float* sbbuf = q2buf + B;                            // B floats

    build_queries<<<B, 64, 0, stream>>>(ent, rrot, rtrans, ebias, trip,
                                        qb, q2buf, sbbuf);
    score_mfma<<<E / 128, 256, 0, stream>>>(ent, ebias, qb, q2buf, sbbuf, out, E);
}

// Round 9
// 150.703 us; speedup vs baseline: 1.0299x; 1.0299x over previous
//
#include <hip/hip_runtime.h>
#include <math.h>

#define C_C   0.01f
#define SQC   0.1f          // sqrt(c)
#define EPSF  1e-15f
#define TCLIP (1.0f - 1e-6f)

typedef short short8 __attribute__((ext_vector_type(8)));
typedef float f32x4  __attribute__((ext_vector_type(4)));

__device__ __forceinline__ float wred(float v) {
#pragma unroll
    for (int off = 32; off > 0; off >>= 1) v += __shfl_xor(v, off, 64);
    return v;
}

__device__ __forceinline__ float dot4(const float4& a, const float4& b) {
    return a.x * b.x + a.y * b.y + a.z * b.z + a.w * b.w;
}

// fp32 -> bf16 round-nearest-even, raw bits
__device__ __forceinline__ unsigned int f2bf(float f) {
    unsigned int u = __float_as_uint(f);
    u += 0x7fffu + ((u >> 16) & 1u);
    return u >> 16;
}
__device__ __forceinline__ unsigned int pk2(float a, float b) {
    return f2bf(a) | (f2bf(b) << 16);
}

// ---------------------------------------------------------------------------
// Kernel 1: build 128 queries; emit bf16 rows + fp32 q2 + subject bias.
// One wave per query.
// ---------------------------------------------------------------------------
__global__ __launch_bounds__(64)
void build_queries(const float* __restrict__ ent,
                   const float* __restrict__ rrot,
                   const float* __restrict__ rtrans,
                   const float* __restrict__ ebias,
                   const int* __restrict__ trip,
                   unsigned short* __restrict__ qb,  // [B][512] bf16 bits
                   float* __restrict__ q2buf,        // [B]
                   float* __restrict__ sbbuf)        // [B]
{
    const int b    = blockIdx.x;
    const int lane = threadIdx.x;
    const int t0   = trip[b * 3 + 0];
    const int r    = trip[b * 3 + 1];

    const float* srow = ent + (size_t)t0 * 512;
    float4 s0 = *(const float4*)(srow + 4 * lane);
    float4 s1 = *(const float4*)(srow + 256 + 4 * lane);

    // log_map_zero
    float ss = dot4(s0, s0) + dot4(s1, s1);
    ss = wred(ss);
    float yn  = fmaxf(sqrtf(ss), EPSF);
    float arg = fminf(SQC * yn, TCLIP);
    float fl  = atanhf(arg) / (SQC * yn);

    // givens rotation on s_tan = fl * s
    const float* arow = rrot + (size_t)r * 256;
    float2 a01 = *(const float2*)(arow + 2 * lane);
    float2 a23 = *(const float2*)(arow + 128 + 2 * lane);
    float c0, n0, c1, n1, c2, n2, c3, n3;
    sincosf(a01.x, &n0, &c0);
    sincosf(a01.y, &n1, &c1);
    sincosf(a23.x, &n2, &c2);
    sincosf(a23.y, &n3, &c3);

    float t0x = s0.x * fl, t0y = s0.y * fl, t0z = s0.z * fl, t0w = s0.w * fl;
    float t1x = s1.x * fl, t1y = s1.y * fl, t1z = s1.z * fl, t1w = s1.w * fl;

    float4 r0, r1;
    r0.x = c0 * t0x - n0 * t0y;  r0.y = n0 * t0x + c0 * t0y;
    r0.z = c1 * t0z - n1 * t0w;  r0.w = n1 * t0z + c1 * t0w;
    r1.x = c2 * t1x - n2 * t1y;  r1.y = n2 * t1x + c2 * t1y;
    r1.z = c3 * t1z - n3 * t1w;  r1.w = n3 * t1z + c3 * t1w;

    // exp_map_zero(rot)
    float vv = dot4(r0, r0) + dot4(r1, r1);
    vv = wred(vv);
    float vn = fmaxf(sqrtf(vv), EPSF);
    float fx = tanhf(SQC * vn) / (SQC * vn);

    // exp_map_zero(rel_trans)
    const float* trow = rtrans + (size_t)r * 512;
    float4 u0 = *(const float4*)(trow + 4 * lane);
    float4 u1 = *(const float4*)(trow + 256 + 4 * lane);
    float tt = dot4(u0, u0) + dot4(u1, u1);
    float rt = dot4(r0, u0) + dot4(r1, u1);
    tt = wred(tt);
    rt = wred(rt);
    float tn = fmaxf(sqrtf(tt), EPSF);
    float fy = tanhf(SQC * tn) / (SQC * tn);

    // mobius_add(x = fx*rot, y = fy*trans)
    float x2 = fx * fx * vv;
    float y2 = fy * fy * tt;
    float xy = fx * fy * rt;
    float ca  = 1.0f + 2.0f * C_C * xy + C_C * y2;
    float cb  = 1.0f - C_C * x2;
    float den = fmaxf(1.0f + 2.0f * C_C * xy + C_C * C_C * x2 * y2, EPSF);
    float inv = 1.0f / den;

    float4 q0, q1;
    q0.x = (ca * fx * r0.x + cb * fy * u0.x) * inv;
    q0.y = (ca * fx * r0.y + cb * fy * u0.y) * inv;
    q0.z = (ca * fx * r0.z + cb * fy * u0.z) * inv;
    q0.w = (ca * fx * r0.w + cb * fy * u0.w) * inv;
    q1.x = (ca * fx * r1.x + cb * fy * u1.x) * inv;
    q1.y = (ca * fx * r1.y + cb * fy * u1.y) * inv;
    q1.z = (ca * fx * r1.z + cb * fy * u1.z) * inv;
    q1.w = (ca * fx * r1.w + cb * fy * u1.w) * inv;

    float qq = dot4(q0, q0) + dot4(q1, q1);
    qq = wred(qq);

    unsigned short* qrow = qb + (size_t)b * 512;
    uint2 h0, h1;
    h0.x = pk2(q0.x, q0.y);  h0.y = pk2(q0.z, q0.w);
    h1.x = pk2(q1.x, q1.y);  h1.y = pk2(q1.z, q1.w);
    *(uint2*)(qrow + 4 * lane)       = h0;
    *(uint2*)(qrow + 256 + 4 * lane) = h1;
    if (lane == 0) {
        q2buf[b] = qq;
        sbbuf[b] = ebias[t0];
    }
}

// ---------------------------------------------------------------------------
// Kernel 2: bf16-MFMA scoring, pipelined, occupancy-first.
// Block = 128 q x 64 e  -> grid 640 (2.5 blocks/CU avg), 4 waves (2x2),
// wave tile 64x32, BK=64 (8 K-slabs).
// Double-buffered LDS (2 x (16KB Q + 8KB E) = 48.25KB -> 3 blocks/CU) +
// register prefetch: per iter: issue global loads(t+1) -> MFMA on LDS[cur]
// -> convert+write LDS[cur^1] -> ONE barrier.
// 16B LDS slots XOR-swizzled by (row&7)<<4 (conflict-free b128 r/w).
// e2 accumulated in fp32 during conversion; 4-thread shfl reduce at end.
// __launch_bounds__(256,3) caps VGPR so 3 blocks/CU stay resident.
// ---------------------------------------------------------------------------
__global__ __launch_bounds__(256, 3)
void score_mfma(const float* __restrict__ ent,
                const float* __restrict__ ebias,
                const unsigned short* __restrict__ qb,
                const float* __restrict__ q2buf,
                const float* __restrict__ sbbuf,
                float* __restrict__ out, int E)
{
    __shared__ unsigned short qs[2][128 * 64];  // 2 x 16 KB
    __shared__ unsigned short es[2][64 * 64];   // 2 x 8 KB
    __shared__ float e2s[64];

    const int tid  = threadIdx.x;
    const int lane = tid & 63;
    const int wid  = tid >> 6;   // 0..3
    const int wr   = wid >> 1;   // q half (64 rows)
    const int wc   = wid & 1;    // e half (32 cols)
    const int e0   = blockIdx.x * 64;

    const int qrow = tid >> 1;   // 0..127, Q staging row
    const int qhal = tid & 1;    // Q staging col half (32 elems)
    const int erow = tid >> 2;   // 0..63, E staging row
    const int equr = tid & 3;    // E staging quarter (16 elems)

    f32x4 acc[4][2];
#pragma unroll
    for (int mi = 0; mi < 4; ++mi)
#pragma unroll
        for (int nj = 0; nj < 2; ++nj) acc[mi][nj] = (f32x4)0.0f;

    uint4  qreg[4];
    float4 ereg[4];
    float  e2p = 0.0f;

    const unsigned short* qsrc0 = qb + (size_t)qrow * 512 + qhal * 32;
    const float*          esrc0 = ent + (size_t)(e0 + erow) * 512 + equr * 16;

#define LOAD_TILES(K0)                                                       \
    {                                                                        \
        const unsigned short* qsrc = qsrc0 + (K0);                           \
        _Pragma("unroll")                                                    \
        for (int c = 0; c < 4; ++c) qreg[c] = *(const uint4*)(qsrc + c * 8); \
        const float* esrc = esrc0 + (K0);                                    \
        _Pragma("unroll")                                                    \
        for (int c = 0; c < 4; ++c) ereg[c] = *(const float4*)(esrc + c * 4);\
    }

#define STORE_TILES(BUF)                                                     \
    {                                                                        \
        _Pragma("unroll")                                                    \
        for (int c = 0; c < 4; ++c) {                                        \
            int off = qrow * 128 + ((((qhal * 4 + c) * 16)) ^ ((qrow & 7) << 4)); \
            *(uint4*)((char*)qs[BUF] + off) = qreg[c];                       \
        }                                                                    \
        _Pragma("unroll")                                                    \
        for (int p = 0; p < 2; ++p) {                                        \
            float4 f0 = ereg[2 * p], f1 = ereg[2 * p + 1];                   \
            e2p += dot4(f0, f0) + dot4(f1, f1);                              \
            uint4 pkd = { pk2(f0.x, f0.y), pk2(f0.z, f0.w),                  \
                          pk2(f1.x, f1.y), pk2(f1.z, f1.w) };                \
            int off = erow * 128 + ((((equr * 2 + p) * 16)) ^ ((erow & 7) << 4)); \
            *(uint4*)((char*)es[BUF] + off) = pkd;                           \
        }                                                                    \
    }

    // prologue: slab 0
    LOAD_TILES(0);
    STORE_TILES(0);
    __syncthreads();

    int cur = 0;
#pragma unroll
    for (int t = 0; t < 8; ++t) {
        if (t < 7) LOAD_TILES((t + 1) * 64);

        // compute on LDS[cur]
#pragma unroll
        for (int ks = 0; ks < 2; ++ks) {
            const int kb = (ks * 4 + (lane >> 4)) * 16;  // 16B slot byte off
            short8 a[4], b[2];
#pragma unroll
            for (int mi = 0; mi < 4; ++mi) {
                int r = wr * 64 + mi * 16 + (lane & 15);
                a[mi] = *(const short8*)((const char*)qs[cur] +
                         r * 128 + (kb ^ ((r & 7) << 4)));
            }
#pragma unroll
            for (int nj = 0; nj < 2; ++nj) {
                int r = wc * 32 + nj * 16 + (lane & 15);
                b[nj] = *(const short8*)((const char*)es[cur] +
                         r * 128 + (kb ^ ((r & 7) << 4)));
            }
#pragma unroll
            for (int mi = 0; mi < 4; ++mi)
#pragma unroll
                for (int nj = 0; nj < 2; ++nj)
                    acc[mi][nj] = __builtin_amdgcn_mfma_f32_16x16x32_bf16(
                        a[mi], b[nj], acc[mi][nj], 0, 0, 0);
        }

        if (t < 7) STORE_TILES(cur ^ 1);
        __syncthreads();
        cur ^= 1;
    }

    // e2: 4 threads (quarters) share one entity row
    e2p += __shfl_xor(e2p, 1, 64);
    e2p += __shfl_xor(e2p, 2, 64);
    if (equr == 0) e2s[erow] = e2p;
    __syncthreads();

    // epilogue: closed-form mobius distance
    float e2v[2], bev[2];
#pragma unroll
    for (int nj = 0; nj < 2; ++nj) {
        int ecol = wc * 32 + nj * 16 + (lane & 15);
        e2v[nj] = e2s[ecol];
        bev[nj] = ebias[e0 + ecol];
    }
#pragma unroll
    for (int mi = 0; mi < 4; ++mi) {
        const int qbase = wr * 64 + mi * 16 + (lane >> 4) * 4;
        float q2a[4], sba[4];
#pragma unroll
        for (int r = 0; r < 4; ++r) {
            q2a[r] = q2buf[qbase + r];
            sba[r] = sbbuf[qbase + r];
        }
#pragma unroll
        for (int nj = 0; nj < 2; ++nj) {
            const int ecol = e0 + wc * 32 + nj * 16 + (lane & 15);
            const float e2 = e2v[nj];
            const float be = bev[nj];
#pragma unroll
            for (int r = 0; r < 4; ++r) {
                float q2  = q2a[r];
                float xy  = -acc[mi][nj][r];
                float ca  = 1.0f + 2.0f * C_C * xy + C_C * e2;
                float cb  = 1.0f - C_C * q2;
                float den = fmaxf(1.0f + 2.0f * C_C * xy + C_C * C_C * q2 * e2, EPSF);
                float id2 = 1.0f / (den * den);
                float dist = (ca * ca * q2 + 2.0f * ca * cb * xy + cb * cb * e2) * id2;
                out[(size_t)(qbase + r) * E + ecol] = sba[r] + be - dist;
            }
        }
    }
#undef LOAD_TILES
#undef STORE_TILES
}

extern "C" void kernel_launch(void* const* d_in, const int* in_sizes, int n_in,
                              void* d_out, int out_size, void* d_ws, size_t ws_size,
                              hipStream_t stream) {
    const float* ent    = (const float*)d_in[0];
    // d_in[1] = rel_embedding: unused by the reference
    const float* rrot   = (const float*)d_in[2];
    const float* rtrans = (const float*)d_in[3];
    const float* ebias  = (const float*)d_in[4];
    const int*   trip   = (const int*)d_in[5];
    float* out = (float*)d_out;

    const int B = in_sizes[5] / 3;    // 128
    const int E = in_sizes[0] / 512;  // 40960

    unsigned short* qb = (unsigned short*)d_ws;          // B*512 bf16
    float* q2buf = (float*)(qb + (size_t)B * 512);       // B floats
    float* sbbuf = q2buf + B;                            // B floats

    build_queries<<<B, 64, 0, stream>>>(ent, rrot, rtrans, ebias, trip,
                                        qb, q2buf, sbbuf);
    score_mfma<<<E / 64, 256, 0, stream>>>(ent, ebias, qb, q2buf, sbbuf, out, E);
}